// Round 6
// baseline (394.850 us; speedup 1.0000x reference)
//
#include <hip/hip_runtime.h>
#include <hip/hip_bf16.h>
#include <cstdint>
#include <cstddef>

#define BATCH 2
#define S_LEN 2048
#define HID   2048
#define NH    16
#define HD    128
#define GK    2048          // K of all projections
#define NT    (GK / 64)     // 32 K-tiles of 64
#define NIT   (NT / 2)      // 16 iterations, 2 K-tiles each
#define ATT_TILES2 (16 * NH * BATCH)  // 16 q-tiles(128 rows) x 32 (b,h) = 512

typedef short bf16x8 __attribute__((ext_vector_type(8)));
typedef float f32x4  __attribute__((ext_vector_type(4)));

__device__ inline unsigned short f2bf(float f) {
    unsigned int u = __float_as_uint(f);
    unsigned int r = (u + 0x7fffu + ((u >> 16) & 1u)) >> 16;
    return (unsigned short)r;
}

// ---------------- fp32 -> bf16 convert, 8 elems/thread ----------------
__global__ __launch_bounds__(256) void conv_f32_bf16(const float* __restrict__ src,
                                                     unsigned short* __restrict__ dst,
                                                     long n) {
    long i = ((long)blockIdx.x * 256 + threadIdx.x) * 8;
    if (i >= n) return;
    const float4 a = *(const float4*)(src + i);
    const float4 b = *(const float4*)(src + i + 4);
    union { unsigned short u[8]; bf16x8 v; } o;
    o.u[0] = f2bf(a.x); o.u[1] = f2bf(a.y); o.u[2] = f2bf(a.z); o.u[3] = f2bf(a.w);
    o.u[4] = f2bf(b.x); o.u[5] = f2bf(b.y); o.u[6] = f2bf(b.z); o.u[7] = f2bf(b.w);
    *(bf16x8*)(dst + i) = o.v;
}

__global__ __launch_bounds__(256) void conv4_f32_bf16(const float* __restrict__ s0,
                                                      const float* __restrict__ s1,
                                                      const float* __restrict__ s2,
                                                      const float* __restrict__ s3,
                                                      unsigned short* __restrict__ d0,
                                                      unsigned short* __restrict__ d1,
                                                      unsigned short* __restrict__ d2,
                                                      unsigned short* __restrict__ d3,
                                                      long n) {
    const int z = blockIdx.y;
    const float* src = (z == 0) ? s0 : (z == 1) ? s1 : (z == 2) ? s2 : s3;
    unsigned short* dst = (z == 0) ? d0 : (z == 1) ? d1 : (z == 2) ? d2 : d3;
    long i = ((long)blockIdx.x * 256 + threadIdx.x) * 8;
    if (i >= n) return;
    const float4 a = *(const float4*)(src + i);
    const float4 b = *(const float4*)(src + i + 4);
    union { unsigned short u[8]; bf16x8 v; } o;
    o.u[0] = f2bf(a.x); o.u[1] = f2bf(a.y); o.u[2] = f2bf(a.z); o.u[3] = f2bf(a.w);
    o.u[4] = f2bf(b.x); o.u[5] = f2bf(b.y); o.u[6] = f2bf(b.z); o.u[7] = f2bf(b.w);
    *(bf16x8*)(dst + i) = o.v;
}

__global__ void zero_int(int* p) { *p = 0; }

// =====================================================================
// 256x128 GEMM, 4-phase cross-phase-pipelined (frozen; see round-5 note:
// two different schedules measured identical -> structural limit).
// =====================================================================

#define STAGE(DU, SRC, KT, H) do {                                            \
    const unsigned short* _s0 = (SRC) + (size_t)((H) * 128) * GK + (KT) * 64; \
    __builtin_amdgcn_global_load_lds(                                         \
        (const __attribute__((address_space(1))) void*)_s0,                   \
        (__attribute__((address_space(3))) void*)(Sm + (DU) + (H) * 8192 + sdst), \
        16, 0, 0);                                                            \
    __builtin_amdgcn_global_load_lds(                                         \
        (const __attribute__((address_space(1))) void*)(_s0 + (size_t)64 * GK), \
        (__attribute__((address_space(3))) void*)(Sm + (DU) + (H) * 8192 + 4096 + sdst), \
        16, 0, 0);                                                            \
} while (0)

#define READ_AF(D, AB) do { _Pragma("unroll")                                 \
    for (int mi = 0; mi < 4; ++mi) {                                          \
        const int r_ = wm * 64 + mi * 16 + ln;                                \
        AB[mi][0] = *(const bf16x8*)&Sm[(D) * 24576 + r_ * 64 + sw0];         \
        AB[mi][1] = *(const bf16x8*)&Sm[(D) * 24576 + r_ * 64 + sw1];         \
    } } while (0)

#define READ_BH(D, BB, HH) do { _Pragma("unroll")                             \
    for (int ni = 0; ni < 2; ++ni) {                                          \
        const int r_ = wn * 64 + ((HH) * 2 + ni) * 16 + ln;                   \
        BB[ni][0] = *(const bf16x8*)&Sm[(D) * 24576 + 16384 + r_ * 64 + sw0]; \
        BB[ni][1] = *(const bf16x8*)&Sm[(D) * 24576 + 16384 + r_ * 64 + sw1]; \
    } } while (0)

#define MFMA_H(AB, BB, HH) do { _Pragma("unroll")                             \
    for (int mi = 0; mi < 4; ++mi) _Pragma("unroll")                          \
    for (int ni = 0; ni < 2; ++ni) _Pragma("unroll")                          \
    for (int ks = 0; ks < 2; ++ks)                                            \
        acc[mi][(HH)*2+ni] = __builtin_amdgcn_mfma_f32_16x16x32_bf16(         \
            AB[mi][ks], BB[ni][ks], acc[mi][(HH)*2+ni], 0, 0, 0);             \
} while (0)

#define PRIO1 __builtin_amdgcn_s_setprio(1)
#define PRIO0 __builtin_amdgcn_s_setprio(0)
#define BAR   __builtin_amdgcn_s_barrier()
#define VM0   asm volatile("s_waitcnt vmcnt(0)" ::: "memory")

// mode 0: bf16 -> [b,h,s,d]; mode 1: bf16 -> [b,h,d,s] (LDS repack);
// mode 2: fp32 -> [m][HID]
__device__ __forceinline__ void gemm256_core(const unsigned short* __restrict__ A,
                                             const unsigned short* __restrict__ Bw,
                                             const float* __restrict__ bias,
                                             void* __restrict__ Cout,
                                             int mode, int M0, int N0,
                                             unsigned short* Sm) {
    const int tid  = threadIdx.x;
    const int lane = tid & 63;
    const int wave = tid >> 6;
    const int ln = lane & 15, g = lane >> 4;
    const int wm = wave & 3, wn = wave >> 2;

    const int strow = tid >> 3;
    const int stcol = (((tid & 7) ^ ((tid >> 3) & 7)) << 3);
    const unsigned short* gA = A  + (size_t)(M0 + strow) * GK + stcol;
    const unsigned short* gB = Bw + (size_t)(N0 + strow) * GK + stcol;
    const int sdst = wave * 512;

    const int sw0 = ((g    ) ^ (ln & 7)) << 3;
    const int sw1 = ((g + 4) ^ (ln & 7)) << 3;

    f32x4 acc[4][4];
#pragma unroll
    for (int i = 0; i < 4; ++i)
#pragma unroll
        for (int j = 0; j < 4; ++j) acc[i][j] = (f32x4){0.f, 0.f, 0.f, 0.f};
    bf16x8 aE[4][2], aO[4][2], bA[2][2], bB[2][2];

    STAGE(0,     gA, 0, 0); STAGE(0,     gA, 0, 1);   // T0.A
    STAGE(16384, gB, 0, 0);                            // T0.B
    STAGE(24576, gA, 1, 0); STAGE(24576, gA, 1, 1);    // T1.A
    asm volatile("s_waitcnt vmcnt(4)" ::: "memory");
    BAR;
    READ_AF(0, aE); READ_BH(0, bA, 0);

    for (int it = 0; it < NIT; ++it) {
        const int kt1 = 2 * it + 1;
        const int kt2 = (2 * it + 2 < NT) ? 2 * it + 2 : NT - 1;
        const int kt3 = (2 * it + 3 < NT) ? 2 * it + 3 : NT - 1;
        // Ph0
        BAR;
        STAGE(24576 + 16384, gB, kt1, 0);
        READ_BH(0, bB, 1);
        PRIO1; MFMA_H(aE, bA, 0); PRIO0;
        // Ph1
        VM0;
        BAR;
        STAGE(0, gA, kt2, 0); STAGE(0, gA, kt2, 1);
        READ_AF(1, aO); READ_BH(1, bA, 0);
        PRIO1; MFMA_H(aE, bB, 1); PRIO0;
        // Ph2
        BAR;
        STAGE(16384, gB, kt2, 0);
        READ_BH(1, bB, 1);
        PRIO1; MFMA_H(aO, bA, 0); PRIO0;
        // Ph3
        VM0;
        BAR;
        STAGE(24576, gA, kt3, 0); STAGE(24576, gA, kt3, 1);
        READ_AF(0, aE); READ_BH(0, bA, 0);
        PRIO1; MFMA_H(aO, bB, 1); PRIO0;
    }
    asm volatile("s_waitcnt vmcnt(0)" ::: "memory");
    __syncthreads();

    if (mode == 0) {
        const int bb = M0 >> 11;
        const int sb = M0 & (S_LEN - 1);
        const int h  = N0 >> 7;
#pragma unroll
        for (int nf = 0; nf < 4; ++nf) {
            const int d = wn * 64 + nf * 16 + ln;
            const float bn = bias[N0 + d];
            unsigned short* dst = (unsigned short*)Cout +
                (((size_t)(bb * NH + h) * S_LEN + sb + wm * 64) * HD + d);
#pragma unroll
            for (int mf = 0; mf < 4; ++mf)
#pragma unroll
                for (int r = 0; r < 4; ++r)
                    dst[(size_t)(mf * 16 + g * 4 + r) * HD] = f2bf(acc[mf][nf][r] + bn);
        }
    } else if (mode == 2) {
        float* dst = (float*)Cout;
#pragma unroll
        for (int nf = 0; nf < 4; ++nf) {
            const int n = N0 + wn * 64 + nf * 16 + ln;
            const float bn = bias[n];
#pragma unroll
            for (int mf = 0; mf < 4; ++mf)
#pragma unroll
                for (int r = 0; r < 4; ++r) {
                    const int m = M0 + wm * 64 + mf * 16 + g * 4 + r;
                    dst[(size_t)m * HID + n] = acc[mf][nf][r] + bn;
                }
        }
    } else {
        const int bb = M0 >> 11;
        const int sb = M0 & (S_LEN - 1);
        const int h  = N0 >> 7;
#pragma unroll
        for (int p = 0; p < 2; ++p) {
            if ((wm >> 1) == p) {
#pragma unroll
                for (int nf = 0; nf < 4; ++nf) {
                    const int dl = wn * 64 + nf * 16 + ln;
                    const float bn = bias[N0 + dl];
#pragma unroll
                    for (int mf = 0; mf < 4; ++mf) {
                        const int sl = (wm & 1) * 64 + mf * 16 + g * 4;
                        const int cs = (sl >> 3) ^ (dl & 15);
                        union { unsigned short u[4]; unsigned long long q; } pk;
#pragma unroll
                        for (int r = 0; r < 4; ++r) pk.u[r] = f2bf(acc[mf][nf][r] + bn);
                        *(unsigned long long*)&Sm[dl * 128 + cs * 8 + (sl & 7)] = pk.q;
                    }
                }
            }
            __syncthreads();
            {
                const int dl = tid >> 2;
                unsigned short* dst = (unsigned short*)Cout +
                    ((size_t)(bb * NH + h) * HD + dl) * S_LEN + sb + p * 128;
#pragma unroll
                for (int jj = 0; jj < 4; ++jj) {
                    const int sc = (tid & 3) + jj * 4;
                    const int cs = sc ^ (dl & 15);
                    *(bf16x8*)(dst + sc * 8) = *(const bf16x8*)&Sm[dl * 128 + cs * 8];
                }
            }
            __syncthreads();
        }
    }
}

__global__ __launch_bounds__(512, 2) void gemm_qkv256(
        const unsigned short* __restrict__ A,
        const unsigned short* __restrict__ w0, const unsigned short* __restrict__ w1,
        const unsigned short* __restrict__ w2,
        const float* __restrict__ b0, const float* __restrict__ b1,
        const float* __restrict__ b2,
        void* o0, void* o1, void* o2) {
    extern __shared__ __align__(16) unsigned short Sm[];
    const int z = blockIdx.z;
    const unsigned short* Bw = (z == 0) ? w0 : (z == 1) ? w1 : w2;
    const float* bias = (z == 0) ? b0 : (z == 1) ? b1 : b2;
    void* Cout = (z == 0) ? o0 : (z == 1) ? o1 : o2;
    gemm256_core(A, Bw, bias, Cout, (z == 2) ? 1 : 0,
                 blockIdx.y * 256, blockIdx.x * 128, Sm);
}

__global__ __launch_bounds__(512, 2) void gemm_out256(
        const unsigned short* __restrict__ A, const unsigned short* __restrict__ Bw,
        const float* __restrict__ bias, float* __restrict__ Cout) {
    extern __shared__ __align__(16) unsigned short Sm[];
    gemm256_core(A, Bw, bias, Cout, 2, blockIdx.y * 256, blockIdx.x * 128, Sm);
}

// ---------------- causal flash attention v4: 32 q-rows per wave ------------
// Q,K: [B,NH,S,HD] bf16 ; Vt: [B,NH,HD,S] bf16 ; O: [B,S,HID] bf16
// CHANGE vs v3 (which measured ~110us, LDS-BW-bound): each wave now owns
// 32 q-rows (2 M-frags) -> every K/V LDS fragment read feeds 2 MFMAs
// instead of 1, halving LDS read traffic per unit of work; per-wave ILP
// doubles (68 MFMA/iter).  Block = 4 waves = 128-row q-tile; 512 tiles;
// grid 256 (1 block/CU, LDS 82.4KB); LPT ticket: avg 34 iter-units/block
// vs max tile 32 -> ~95% balance.  Staging, swizzles, softmax numerics,
// and per-element accumulation order IDENTICAL to v3 (absmax canary).
// kv loop: kt = 0 .. 2qt+1; mask tiles krel = kt-2qt >= 0:
//   key_local = krel*64 + nc*16+ln  >  row_local = wave*32+mi*16+g*4+r.
__global__ __launch_bounds__(256, 1) void attn_kernel(const unsigned short* __restrict__ Q,
                                                      const unsigned short* __restrict__ Kk,
                                                      const unsigned short* __restrict__ Vt,
                                                      unsigned short* __restrict__ O,
                                                      int* __restrict__ ticket) {
    __shared__ __align__(16) unsigned short Ks[2 * 64 * 128];  // [buf][key][d], chunk^=(key&15)
    __shared__ __align__(16) unsigned short Vs[2 * 128 * 64];  // [buf][d][key], chunk^=(d&7)
    __shared__ __align__(16) unsigned short Pl[4][32 * 72];    // per-wave P (32 rows), stride 72
    __shared__ int tsh;
    const int tid = threadIdx.x;
    const int lane = tid & 63;
    const int wave = tid >> 6;
    const int g = lane >> 4, ln = lane & 15;
    const float scale2 = 0.08838834764831845f * 1.4426950408889634f;  // 1/sqrt(128)*log2(e)
    const bf16x8 ones_v = {0x3F80, 0x3F80, 0x3F80, 0x3F80, 0x3F80, 0x3F80, 0x3F80, 0x3F80};

    const int kcol = ((tid & 15) ^ ((tid >> 4) & 15)) * 8;   // K: 16 chunks/row
    const int vcol = ((tid & 7) ^ ((tid >> 3) & 7)) * 8;     // V: 8 chunks/row

    for (;;) {
        if (tid == 0) tsh = atomicAdd(ticket, 1);
        __syncthreads();
        const int t = tsh;
        if (t >= ATT_TILES2) break;
        const int qt = 15 - (t >> 5);       // LPT: big q-tiles (128 rows) first
        const int bh = t & 31;
        const int qbase = qt * 128 + wave * 32;

        const unsigned short* Qp = Q  + (size_t)bh * S_LEN * HD;
        const unsigned short* Kp = Kk + (size_t)bh * S_LEN * HD;
        const unsigned short* Vp = Vt + (size_t)bh * HD * S_LEN;

        // Q fragments: 2 m-frags x 4 d-chunks (8 global b128; drained at kt=0)
        bf16x8 aq[2][4];
#pragma unroll
        for (int mi = 0; mi < 2; ++mi)
#pragma unroll
            for (int dc = 0; dc < 4; ++dc)
                aq[mi][dc] = *(const bf16x8*)&Qp[(size_t)(qbase + mi * 16 + ln) * HD + dc * 32 + g * 8];

        f32x4 acc[2][9];
#pragma unroll
        for (int mi = 0; mi < 2; ++mi)
#pragma unroll
            for (int i = 0; i < 9; ++i) acc[mi][i] = (f32x4){0.f, 0.f, 0.f, 0.f};

        // prologue: stage kv tile 0 -> buf0 (8 loads/wave)
#pragma unroll
        for (int i = 0; i < 4; ++i) {
            const unsigned short* gk = Kp + (size_t)(i * 16 + (tid >> 4)) * HD + kcol;
            __builtin_amdgcn_global_load_lds(
                (const __attribute__((address_space(1))) void*)gk,
                (__attribute__((address_space(3))) void*)(Ks + i * 2048 + wave * 512),
                16, 0, 0);
        }
#pragma unroll
        for (int i = 0; i < 4; ++i) {
            const unsigned short* gv = Vp + (size_t)(i * 32 + (tid >> 3)) * S_LEN + vcol;
            __builtin_amdgcn_global_load_lds(
                (const __attribute__((address_space(1))) void*)gv,
                (__attribute__((address_space(3))) void*)(Vs + i * 2048 + wave * 512),
                16, 0, 0);
        }

        const int ktmax = 2 * qt + 1;
        for (int kt = 0; kt <= ktmax; ++kt) {
            const int cur = kt & 1;
            const bool do_stage = (kt < ktmax);
            if (do_stage) {
                const int kb2 = (kt + 1) * 64;
                const int nb  = (kt + 1) & 1;
                unsigned short* kdst = Ks + nb * 8192 + wave * 512;
                unsigned short* vdst = Vs + nb * 8192 + wave * 512;
#pragma unroll
                for (int i = 0; i < 4; ++i) {
                    const unsigned short* gk = Kp + (size_t)(kb2 + i * 16 + (tid >> 4)) * HD + kcol;
                    __builtin_amdgcn_global_load_lds(
                        (const __attribute__((address_space(1))) void*)gk,
                        (__attribute__((address_space(3))) void*)(kdst + i * 2048),
                        16, 0, 0);
                }
#pragma unroll
                for (int i = 0; i < 4; ++i) {
                    const unsigned short* gv = Vp + (size_t)(i * 32 + (tid >> 3)) * S_LEN + kb2 + vcol;
                    __builtin_amdgcn_global_load_lds(
                        (const __attribute__((address_space(1))) void*)gv,
                        (__attribute__((address_space(3))) void*)(vdst + i * 2048),
                        16, 0, 0);
                }
            }
            if (kt == 0 || !do_stage) {
                asm volatile("s_waitcnt vmcnt(0)" ::: "memory");
            } else {
                asm volatile("s_waitcnt vmcnt(8)" ::: "memory");
            }
            __builtin_amdgcn_s_barrier();

            const int kbuf = cur * 8192;
            // ---- S tile = Q(32x128) . K^T(128x64): K-frag shared by 2 mi ----
            f32x4 sc[2][4];
            __builtin_amdgcn_s_setprio(1);
#pragma unroll
            for (int nc = 0; nc < 4; ++nc) {
                sc[0][nc] = (f32x4){0.f, 0.f, 0.f, 0.f};
                sc[1][nc] = (f32x4){0.f, 0.f, 0.f, 0.f};
#pragma unroll
                for (int dc = 0; dc < 4; ++dc) {
                    bf16x8 bk = *(const bf16x8*)&Ks[kbuf + (nc * 16 + ln) * 128 + ((dc * 4 + g) ^ ln) * 8];
                    sc[0][nc] = __builtin_amdgcn_mfma_f32_16x16x32_bf16(aq[0][dc], bk, sc[0][nc], 0, 0, 0);
                    sc[1][nc] = __builtin_amdgcn_mfma_f32_16x16x32_bf16(aq[1][dc], bk, sc[1][nc], 0, 0, 0);
                }
            }
            __builtin_amdgcn_s_setprio(0);
            // ---- P = exp2(s*scale2); mask on/above-diagonal tiles ----
            const int krel = kt - 2 * qt;
#pragma unroll
            for (int mi = 0; mi < 2; ++mi)
#pragma unroll
                for (int nc = 0; nc < 4; ++nc)
#pragma unroll
                    for (int r = 0; r < 4; ++r) {
                        float pv = __builtin_amdgcn_exp2f(sc[mi][nc][r] * scale2);
                        if (krel >= 0 &&
                            (krel * 64 + nc * 16 + ln > wave * 32 + mi * 16 + g * 4 + r))
                            pv = 0.f;
                        Pl[wave][(mi * 16 + g * 4 + r) * 72 + nc * 16 + ln] = f2bf(pv);
                    }
            // ---- O += P(32x64) . V(64x128): V-frag shared by 2 mi ----
            __builtin_amdgcn_s_setprio(1);
#pragma unroll
            for (int kc = 0; kc < 2; ++kc) {
                bf16x8 ap0 = *(const bf16x8*)&Pl[wave][(     ln) * 72 + kc * 32 + g * 8];
                bf16x8 ap1 = *(const bf16x8*)&Pl[wave][(16 + ln) * 72 + kc * 32 + g * 8];
#pragma unroll
                for (int d2 = 0; d2 < 8; ++d2) {
                    bf16x8 bv = *(const bf16x8*)&Vs[kbuf + (d2 * 16 + ln) * 64 + ((kc * 4 + g) ^ (ln & 7)) * 8];
                    acc[0][d2] = __builtin_amdgcn_mfma_f32_16x16x32_bf16(ap0, bv, acc[0][d2], 0, 0, 0);
                    acc[1][d2] = __builtin_amdgcn_mfma_f32_16x16x32_bf16(ap1, bv, acc[1][d2], 0, 0, 0);
                }
                acc[0][8] = __builtin_amdgcn_mfma_f32_16x16x32_bf16(ap0, ones_v, acc[0][8], 0, 0, 0);
                acc[1][8] = __builtin_amdgcn_mfma_f32_16x16x32_bf16(ap1, ones_v, acc[1][8], 0, 0, 0);
            }
            __builtin_amdgcn_s_setprio(0);
            __builtin_amdgcn_s_barrier();   // overwrite gate for buf[kt&1]
        }
        // ---- epilogue: O[b, s, h*HD + d] = acc / rowsum ----
        const int b = bh >> 4, h = bh & 15;
        float inv[2][4];
#pragma unroll
        for (int mi = 0; mi < 2; ++mi)
#pragma unroll
            for (int r = 0; r < 4; ++r) inv[mi][r] = 1.0f / acc[mi][8][r];
#pragma unroll
        for (int mi = 0; mi < 2; ++mi)
#pragma unroll
            for (int d2 = 0; d2 < 8; ++d2)
#pragma unroll
                for (int r = 0; r < 4; ++r) {
                    const int row = qbase + mi * 16 + g * 4 + r;
                    const int col = h * HD + d2 * 16 + ln;
                    O[((size_t)b * S_LEN + row) * HID + col] = f2bf(acc[mi][d2][r] * inv[mi][r]);
                }
    }
}

extern "C" void kernel_launch(void* const* d_in, const int* in_sizes, int n_in,
                              void* d_out, int out_size, void* d_ws, size_t ws_size,
                              hipStream_t stream) {
    const float* x  = (const float*)d_in[0];
    const float* wq = (const float*)d_in[1];
    const float* bq = (const float*)d_in[2];
    const float* wk = (const float*)d_in[3];
    const float* bk = (const float*)d_in[4];
    const float* wv = (const float*)d_in[5];
    const float* bv = (const float*)d_in[6];
    const float* wo = (const float*)d_in[7];
    const float* bo = (const float*)d_in[8];
    float* out = (float*)d_out;

    const long nx = (long)BATCH * S_LEN * HID;  // 8388608
    const long nw = (long)HID * HID;            // 4194304

    char* p = (char*)d_ws;
    unsigned short* xb  = (unsigned short*)p; p += nx * 2;
    unsigned short* wqb = (unsigned short*)p; p += nw * 2;
    unsigned short* wkb = (unsigned short*)p; p += nw * 2;
    unsigned short* wvb = (unsigned short*)p; p += nw * 2;
    unsigned short* wob = (unsigned short*)p; p += nw * 2;
    unsigned short* Qb  = (unsigned short*)p; p += nx * 2;
    unsigned short* Kb  = (unsigned short*)p; p += nx * 2;
    unsigned short* Vtb = (unsigned short*)p; p += nx * 2;
    unsigned short* Ob  = (unsigned short*)p; p += nx * 2;
    int* ticket = (int*)p;

    conv_f32_bf16<<<(int)(nx / 8 / 256), 256, 0, stream>>>(x, xb, nx);
    dim3 cgrid((unsigned)(nw / 8 / 256), 4);
    conv4_f32_bf16<<<cgrid, 256, 0, stream>>>(wq, wk, wv, wo, wqb, wkb, wvb, wob, nw);
    zero_int<<<1, 1, 0, stream>>>(ticket);

    const int M = BATCH * S_LEN;  // 4096
    dim3 qkvgrid(HID / 128, M / 256, 3);   // 16 x 16 x 3 = 768 blocks (3 rounds)
    gemm_qkv256<<<qkvgrid, 512, 98304, stream>>>(xb, wqb, wkb, wvb, bq, bk, bv,
                                                 Qb, Kb, Vtb);

    attn_kernel<<<256, 256, 0, stream>>>(Qb, Kb, Vtb, Ob, ticket);

    dim3 ogrid(HID / 128, M / 256);        // 16 x 16 = 256 blocks (1 round)
    gemm_out256<<<ogrid, 512, 98304, stream>>>(Ob, wob, bo, out);
}